// Round 6
// baseline (410.782 us; speedup 1.0000x reference)
//
#include <hip/hip_runtime.h>

constexpr int B = 4, C = 16, H = 512, W = 512;
constexpr int HW = H * W;
constexpr int TS = 32, TX = 16, TYN = 16;
constexpr int NBINS = B * TYN * TX;   // 1024
constexpr int CAP   = 1344;           // slots per bin (expected max ~1250)
constexpr int CSTR  = 16;             // counter stride in u32 -> 64B per counter
constexpr int REC   = 10;             // u32 words per value-record (40 B)
constexpr int CPB   = 8;              // channels per block (fallback wide path)

__device__ __forceinline__ void fadd(float* p, float v) { unsafeAtomicAdd(p, v); }

// round-to-nearest-even f32 -> bf16 (upper 16 bits)
__device__ __forceinline__ unsigned f2bf(float x) {
    unsigned u = __float_as_uint(x);
    return (u + 0x7FFFu + ((u >> 16) & 1u)) >> 16;
}

// ---- direct global-atomic splat (overflow / fallback paths) ----
__device__ __forceinline__ void direct_splat(
    const float* __restrict__ im0, float* __restrict__ out,
    int b, int s, int xf, int yf,
    float w0, float w1, float w2, float w3, unsigned mask)
{
    size_t base = (size_t)b * C * HW;
    int d00 = yf * W + xf;
    for (int c = 0; c < C; ++c) {
        float v = im0[base + (size_t)c * HW + s];
        float* o = out + base + (size_t)c * HW + d00;
        if (mask & 1u) fadd(o,         v * w0);
        if (mask & 2u) fadd(o + 1,     v * w1);
        if (mask & 4u) fadd(o + W,     v * w2);
        if (mask & 8u) fadd(o + W + 1, v * w3);
    }
}

// ---- wave-aggregated slot allocation: one atomic per (wave, distinct bin) ----
__device__ __forceinline__ unsigned agg_slot(
    bool want, int bin, unsigned* __restrict__ cnt, int lane)
{
    unsigned slot = 0xFFFFFFFFu;
    unsigned long long act = __ballot(want);
    while (act) {
        int leader = (int)__builtin_ctzll(act);
        int lbin = __shfl(bin, leader);
        bool mine = want && (bin == lbin);
        unsigned long long grp = __ballot(mine);
        unsigned base = 0;
        if (lane == leader)
            base = atomicAdd(&cnt[(unsigned)lbin * CSTR], (unsigned)__popcll(grp));
        base = (unsigned)__shfl((int)base, leader);
        if (mine)
            slot = base + (unsigned)__popcll(grp & ((1ull << lane) - 1ull));
        act &= ~grp;
    }
    return slot;   // only meaningful for want-lanes; >=CAP means overflow
}

// =================== PRIMARY PATH: value-carrying records ===================

// Phase 1: coalesced im0 read, pack 16 bf16 values + meta, bin by dest tile
__global__ __launch_bounds__(256) void bin_vals_kernel(
    const float* __restrict__ flow, const float* __restrict__ im0,
    unsigned* __restrict__ cnt, unsigned* __restrict__ entries,
    float* __restrict__ out)
{
    int idx  = blockIdx.x * 256 + threadIdx.x;   // exact grid
    int lane = threadIdx.x & 63;
    float2 f = reinterpret_cast<const float2*>(flow)[idx];
    int sx = idx & (W - 1);
    int sy = (idx >> 9) & (H - 1);
    int b  = idx >> 18;

    float xd = (float)sx + f.x;
    float yd = (float)sy + f.y;
    float xff = floorf(xd), yff = floorf(yd);
    bool valid = (xff >= 0.0f && yff >= 0.0f &&
                  xff <= (float)(W - 2) && yff <= (float)(H - 2));
    int xf = valid ? (int)xff : 0;
    int yf = valid ? (int)yff : 0;
    float ax = xd - xff, ay = yd - yff;

    int s = sy * W + sx;
    int d = yf * W + xf;
    unsigned ax14 = min((unsigned)(ax * 16384.0f), 16383u);
    unsigned ay14 = min((unsigned)(ay * 16384.0f), 16383u);
    unsigned meta1 = (unsigned)d | (ax14 << 18);
    unsigned ay18  = ay14 << 18;

    // coalesced 16-channel read + bf16 pack (8 words)
    unsigned vw[8];
    if (valid) {
        const float* p = im0 + (size_t)b * C * HW + s;
        #pragma unroll
        for (int c = 0; c < 8; ++c) {
            float v0 = p[(size_t)(2 * c)     * HW];
            float v1 = p[(size_t)(2 * c + 1) * HW];
            vw[c] = f2bf(v0) | (f2bf(v1) << 16);
        }
    } else {
        #pragma unroll
        for (int c = 0; c < 8; ++c) vw[c] = 0;
    }

    int txf = xf >> 5, txc = (xf + 1) >> 5;
    int tyf = yf >> 5, tyc = (yf + 1) >> 5;
    bool spx = (txc != txf), spy = (tyc != tyf);
    int binb = b * (TYN * TX);

    unsigned m0 = 1u | (spx ? 0u : 2u) | (spy ? 0u : 4u) | ((!spx && !spy) ? 8u : 0u);
    unsigned m1 = 2u | (spy ? 0u : 8u);
    unsigned m2 = 4u | (spx ? 0u : 8u);
    unsigned m3 = 8u;

    unsigned ovf = 0;
    #pragma unroll
    for (int k = 0; k < 4; ++k) {
        bool want; int bin; unsigned mk;
        if (k == 0)      { want = valid;               bin = binb + tyf * TX + txf; mk = m0; }
        else if (k == 1) { want = valid && spx;        bin = binb + tyf * TX + txc; mk = m1; }
        else if (k == 2) { want = valid && spy;        bin = binb + tyc * TX + txf; mk = m2; }
        else             { want = valid && spx && spy; bin = binb + tyc * TX + txc; mk = m3; }

        unsigned slot = agg_slot(want, bin, cnt, lane);
        if (want) {
            if (slot < CAP) {
                unsigned* rec = entries + ((size_t)bin * CAP + slot) * REC;
                uint2* r2 = reinterpret_cast<uint2*>(rec);
                r2[0] = make_uint2(meta1, mk | ay18);
                r2[1] = make_uint2(vw[0], vw[1]);
                r2[2] = make_uint2(vw[2], vw[3]);
                r2[3] = make_uint2(vw[4], vw[5]);
                r2[4] = make_uint2(vw[6], vw[7]);
            } else {
                ovf |= mk;
            }
        }
    }

    if (ovf) {  // statistically never
        float u0 = (1.f - ax) * (1.f - ay), u1 = ax * (1.f - ay);
        float u2 = (1.f - ax) * ay,         u3 = ax * ay;
        direct_splat(im0, out, b, s, xf, yf, u0, u1, u2, u3, ovf);
    }
}

// Phase 2: stream records (coalesced), LDS splat all 16 channels, flush
__global__ __launch_bounds__(256) void accum_vals_kernel(
    const unsigned* __restrict__ cnt, const unsigned* __restrict__ entries,
    float* __restrict__ out)
{
    __shared__ float acc[C * TS * TS];   // 64 KB
    const int bin = blockIdx.x;
    const int tid = threadIdx.x;
    const int b  = bin >> 8;
    const int ty = (bin >> 4) & 15;
    const int tx = bin & 15;
    const int y0 = ty * TS, x0 = tx * TS;

    for (int i = tid; i < C * TS * TS; i += 256) acc[i] = 0.0f;
    __syncthreads();

    const int n = min((int)cnt[bin * CSTR], CAP);

    for (int i = tid; i < n; i += 256) {
        const uint2* rec = reinterpret_cast<const uint2*>(
            entries + ((size_t)bin * CAP + i) * REC);
        uint2 m  = rec[0];
        uint2 q0 = rec[1], q1 = rec[2], q2 = rec[3], q3 = rec[4];

        int d = (int)(m.x & 0x3FFFFu);
        float ax = (float)(m.x >> 18) * (1.0f / 16384.0f);
        unsigned mask = m.y & 15u;
        float ay = (float)(m.y >> 18) * (1.0f / 16384.0f);
        int xf = d & (W - 1), yf = d >> 9;
        int l0 = (yf - y0) * TS + (xf - x0);
        float wnw = (1.f - ax) * (1.f - ay), wne = ax * (1.f - ay);
        float wsw = (1.f - ax) * ay,         wse = ax * ay;
        bool p0 = mask & 1u, p1 = mask & 2u, p2 = mask & 4u, p3 = mask & 8u;

        unsigned vw0 = q0.x, vw1 = q0.y, vw2 = q1.x, vw3 = q1.y;
        unsigned vw4 = q2.x, vw5 = q2.y, vw6 = q3.x, vw7 = q3.y;

        #pragma unroll
        for (int c = 0; c < C; ++c) {
            unsigned wv;
            switch (c >> 1) {
                case 0: wv = vw0; break; case 1: wv = vw1; break;
                case 2: wv = vw2; break; case 3: wv = vw3; break;
                case 4: wv = vw4; break; case 5: wv = vw5; break;
                case 6: wv = vw6; break; default: wv = vw7; break;
            }
            float v = __uint_as_float((c & 1) ? (wv & 0xFFFF0000u) : (wv << 16));
            float* a = acc + c * (TS * TS);
            if (p0) fadd(&a[l0],          v * wnw);
            if (p1) fadd(&a[l0 + 1],      v * wne);
            if (p2) fadd(&a[l0 + TS],     v * wsw);
            if (p3) fadd(&a[l0 + TS + 1], v * wse);
        }
    }
    __syncthreads();

    // flush: exclusive tile ownership -> plain float4 RMW (preserves overflow splats)
    size_t outb = (size_t)b * C * HW;
    for (int i = tid; i < (C * TS * TS) / 4; i += 256) {   // 4096 float4
        int c   = i >> 8;
        int rem = i & 255;
        int y   = rem >> 3;
        int x4  = (rem & 7) * 4;
        float4 a = *reinterpret_cast<const float4*>(&acc[c * TS * TS + y * TS + x4]);
        float* op = out + outb + (size_t)c * HW + (size_t)(y0 + y) * W + (x0 + x4);
        float4 cur = *reinterpret_cast<float4*>(op);
        cur.x += a.x; cur.y += a.y; cur.z += a.z; cur.w += a.w;
        *reinterpret_cast<float4*>(op) = cur;
    }
}

// =================== FALLBACK 1: round-5 wide path (11 MB ws) ===================

__global__ __launch_bounds__(256) void bin_wide_kernel(
    const float* __restrict__ flow, const float* __restrict__ im0,
    unsigned* __restrict__ cnt, unsigned* __restrict__ entries,
    float* __restrict__ out)
{
    int idx  = blockIdx.x * 256 + threadIdx.x;
    int lane = threadIdx.x & 63;
    float2 f = reinterpret_cast<const float2*>(flow)[idx];
    int sx = idx & (W - 1);
    int sy = (idx >> 9) & (H - 1);
    int b  = idx >> 18;

    float xd = (float)sx + f.x;
    float yd = (float)sy + f.y;
    float xff = floorf(xd), yff = floorf(yd);
    bool valid = (xff >= 0.0f && yff >= 0.0f &&
                  xff <= (float)(W - 2) && yff <= (float)(H - 2));
    int xf = valid ? (int)xff : 0;
    int yf = valid ? (int)yff : 0;
    float ax = xd - xff, ay = yd - yff;

    int s = sy * W + sx;
    int d = yf * W + xf;
    unsigned ax14 = min((unsigned)(ax * 16384.0f), 16383u);
    unsigned ay14 = min((unsigned)(ay * 16384.0f), 16383u);
    unsigned w0 = (unsigned)s | (ax14 << 18);
    unsigned w1 = (unsigned)d | (ay14 << 18);

    int txf = xf >> 5, txc = (xf + 1) >> 5;
    int tyf = yf >> 5, tyc = (yf + 1) >> 5;
    bool spx = (txc != txf), spy = (tyc != tyf);
    int binb = b * (TYN * TX);

    unsigned m0 = 1u | (spx ? 0u : 2u) | (spy ? 0u : 4u) | ((!spx && !spy) ? 8u : 0u);
    unsigned m1 = 2u | (spy ? 0u : 8u);
    unsigned m2 = 4u | (spx ? 0u : 8u);
    unsigned m3 = 8u;

    unsigned ovf = 0;
    #pragma unroll
    for (int k = 0; k < 4; ++k) {
        bool want; int bin; unsigned mk;
        if (k == 0)      { want = valid;               bin = binb + tyf * TX + txf; mk = m0; }
        else if (k == 1) { want = valid && spx;        bin = binb + tyf * TX + txc; mk = m1; }
        else if (k == 2) { want = valid && spy;        bin = binb + tyc * TX + txf; mk = m2; }
        else             { want = valid && spx && spy; bin = binb + tyc * TX + txc; mk = m3; }
        unsigned slot = agg_slot(want, bin, cnt, lane);
        if (want) {
            if (slot < CAP)
                reinterpret_cast<uint2*>(entries)[(size_t)bin * CAP + slot] =
                    make_uint2(w0, w1);
            else
                ovf |= mk;
        }
    }
    if (ovf) {
        float u0 = (1.f - ax) * (1.f - ay), u1 = ax * (1.f - ay);
        float u2 = (1.f - ax) * ay,         u3 = ax * ay;
        direct_splat(im0, out, b, s, xf, yf, u0, u1, u2, u3, ovf);
    }
}

__global__ __launch_bounds__(256) void accum_wide_kernel(
    const float* __restrict__ im0,
    const unsigned* __restrict__ cnt, const unsigned* __restrict__ entries,
    float* __restrict__ out)
{
    __shared__ float acc[CPB * TS * TS];   // 32 KB
    const int bin = blockIdx.x;
    const int c0  = blockIdx.y * CPB;
    const int tid = threadIdx.x;
    const int b  = bin >> 8;
    const int ty = (bin >> 4) & 15;
    const int tx = bin & 15;
    const int y0 = ty * TS, x0 = tx * TS;

    for (int i = tid; i < CPB * TS * TS; i += 256) acc[i] = 0.0f;
    __syncthreads();

    const int n = min((int)cnt[bin * CSTR], CAP);
    const float* im0b = im0 + (size_t)b * C * HW + (size_t)c0 * HW;

    for (int i = tid; i < n; i += 256) {
        uint2 e = reinterpret_cast<const uint2*>(entries)[(size_t)bin * CAP + i];
        int s = (int)(e.x & 0x3FFFFu);
        int d = (int)(e.y & 0x3FFFFu);
        float ax = (float)(e.x >> 18) * (1.0f / 16384.0f);
        float ay = (float)(e.y >> 18) * (1.0f / 16384.0f);
        int xf = d & (W - 1), yf = d >> 9;
        int lx = xf - x0, ly = yf - y0;
        float wnw = (1.f - ax) * (1.f - ay), wne = ax * (1.f - ay);
        float wsw = (1.f - ax) * ay,         wse = ax * ay;
        bool p0 = (unsigned)lx < (unsigned)TS && (unsigned)ly < (unsigned)TS;
        bool p1 = (unsigned)(lx + 1) < (unsigned)TS && (unsigned)ly < (unsigned)TS;
        bool p2 = (unsigned)lx < (unsigned)TS && (unsigned)(ly + 1) < (unsigned)TS;
        bool p3 = (unsigned)(lx + 1) < (unsigned)TS && (unsigned)(ly + 1) < (unsigned)TS;
        int l0 = ly * TS + lx;

        float v[CPB];
        #pragma unroll
        for (int c = 0; c < CPB; ++c) v[c] = im0b[(size_t)c * HW + s];
        #pragma unroll
        for (int c = 0; c < CPB; ++c) {
            float* a = acc + c * (TS * TS);
            if (p0) fadd(&a[l0],          v[c] * wnw);
            if (p1) fadd(&a[l0 + 1],      v[c] * wne);
            if (p2) fadd(&a[l0 + TS],     v[c] * wsw);
            if (p3) fadd(&a[l0 + TS + 1], v[c] * wse);
        }
    }
    __syncthreads();

    size_t outb = (size_t)b * C * HW + (size_t)c0 * HW;
    for (int i = tid; i < (CPB * TS * TS) / 4; i += 256) {
        int c   = i >> 8;
        int rem = i & 255;
        int y   = rem >> 3;
        int x4  = (rem & 7) * 4;
        float4 a = *reinterpret_cast<const float4*>(&acc[c * TS * TS + y * TS + x4]);
        float* op = out + outb + (size_t)c * HW + (size_t)(y0 + y) * W + (x0 + x4);
        float4 cur = *reinterpret_cast<float4*>(op);
        cur.x += a.x; cur.y += a.y; cur.z += a.z; cur.w += a.w;
        *reinterpret_cast<float4*>(op) = cur;
    }
}

// =================== FALLBACK 2: naive direct-atomic ===================
__global__ __launch_bounds__(256) void warp_naive_kernel(
    const float* __restrict__ im0, const float* __restrict__ flow,
    float* __restrict__ out)
{
    int idx = blockIdx.x * 256 + threadIdx.x;
    if (idx >= B * HW) return;
    int w = idx & (W - 1);
    int h = (idx >> 9) & (H - 1);
    int b = idx >> 18;
    float2 f = reinterpret_cast<const float2*>(flow)[idx];
    float xd = (float)w + f.x, yd = (float)h + f.y;
    float xff = floorf(xd), yff = floorf(yd);
    if (!(xff >= 0.0f && yff >= 0.0f &&
          xff <= (float)(W - 2) && yff <= (float)(H - 2))) return;
    int xf = (int)xff, yf = (int)yff;
    float ax = xd - xff, ay = yd - yff;
    float w0 = (1.f - ax) * (1.f - ay), w1 = ax * (1.f - ay);
    float w2 = (1.f - ax) * ay,         w3 = ax * ay;
    direct_splat(im0, out, b, h * W + w, xf, yf, w0, w1, w2, w3, 15u);
}

extern "C" void kernel_launch(void* const* d_in, const int* in_sizes, int n_in,
                              void* d_out, int out_size, void* d_ws, size_t ws_size,
                              hipStream_t stream) {
    const float* im0  = (const float*)d_in[0];
    const float* flow = (const float*)d_in[1];
    float* out = (float*)d_out;

    hipMemsetAsync(out, 0, (size_t)out_size * sizeof(float), stream);

    constexpr size_t need_cnt  = (size_t)NBINS * CSTR * 4;
    constexpr size_t need_vals = need_cnt + (size_t)NBINS * CAP * REC * 4;  // ~55 MB
    constexpr size_t need_wide = need_cnt + (size_t)NBINS * CAP * 8;        // ~11 MB
    constexpr int total = B * HW;

    if (ws_size < need_wide) {
        warp_naive_kernel<<<(total + 255) / 256, 256, 0, stream>>>(im0, flow, out);
        return;
    }

    unsigned* cnt = (unsigned*)d_ws;
    unsigned* entries = cnt + (size_t)NBINS * CSTR;
    hipMemsetAsync(cnt, 0, need_cnt, stream);

    if (ws_size >= need_vals) {
        bin_vals_kernel<<<total / 256, 256, 0, stream>>>(flow, im0, cnt, entries, out);
        accum_vals_kernel<<<NBINS, 256, 0, stream>>>(cnt, entries, out);
    } else {
        bin_wide_kernel<<<total / 256, 256, 0, stream>>>(flow, im0, cnt, entries, out);
        dim3 agrid(NBINS, C / CPB);
        accum_wide_kernel<<<agrid, 256, 0, stream>>>(im0, cnt, entries, out);
    }
}

// Round 7
// 83.387 us; speedup vs baseline: 4.9262x; 4.9262x over previous
//
#include <hip/hip_runtime.h>

constexpr int B = 4, C = 16, H = 512, W = 512;
constexpr int HW = H * W;
constexpr int TS = 32, TX = 16, TYN = 16;
constexpr int NBINS = B * TYN * TX;   // 1024
constexpr int CAP   = 1280;           // slots per bin (expected max ~1250; overflow -> direct splat)
constexpr int CSTR  = 16;             // counter stride in u32 -> 64B per counter
constexpr int REC   = 10;             // u32 words per value-record (40 B)
constexpr int CPB   = 8;              // channels per block (fallback wide path)

__device__ __forceinline__ void fadd(float* p, float v) { unsafeAtomicAdd(p, v); }

// round-to-nearest-even f32 -> bf16 (upper 16 bits)
__device__ __forceinline__ unsigned f2bf(float x) {
    unsigned u = __float_as_uint(x);
    return (u + 0x7FFFu + ((u >> 16) & 1u)) >> 16;
}
__device__ __forceinline__ float bf_lo(unsigned w) { return __uint_as_float(w << 16); }
__device__ __forceinline__ float bf_hi(unsigned w) { return __uint_as_float(w & 0xFFFF0000u); }

// ---- direct global-atomic splat (overflow / fallback paths) ----
__device__ __forceinline__ void direct_splat(
    const float* __restrict__ im0, float* __restrict__ out,
    int b, int s, int xf, int yf,
    float w0, float w1, float w2, float w3, unsigned mask)
{
    size_t base = (size_t)b * C * HW;
    int d00 = yf * W + xf;
    for (int c = 0; c < C; ++c) {
        float v = im0[base + (size_t)c * HW + s];
        float* o = out + base + (size_t)c * HW + d00;
        if (mask & 1u) fadd(o,         v * w0);
        if (mask & 2u) fadd(o + 1,     v * w1);
        if (mask & 4u) fadd(o + W,     v * w2);
        if (mask & 8u) fadd(o + W + 1, v * w3);
    }
}

// ---- wave-aggregated slot allocation: one atomic per (wave, distinct bin) ----
__device__ __forceinline__ unsigned agg_slot(
    bool want, int bin, unsigned* __restrict__ cnt, int lane)
{
    unsigned slot = 0xFFFFFFFFu;
    unsigned long long act = __ballot(want);
    while (act) {
        int leader = (int)__builtin_ctzll(act);
        int lbin = __shfl(bin, leader);
        bool mine = want && (bin == lbin);
        unsigned long long grp = __ballot(mine);
        unsigned base = 0;
        if (lane == leader)
            base = atomicAdd(&cnt[(unsigned)lbin * CSTR], (unsigned)__popcll(grp));
        base = (unsigned)__shfl((int)base, leader);
        if (mine)
            slot = base + (unsigned)__popcll(grp & ((1ull << lane) - 1ull));
        act &= ~grp;
    }
    return slot;
}

// =================== PRIMARY PATH ===================

// Phase 1: coalesced im0 read, pack 16 bf16 values + meta, bin by dest tile
__global__ __launch_bounds__(256) void bin_vals_kernel(
    const float* __restrict__ flow, const float* __restrict__ im0,
    unsigned* __restrict__ cnt, unsigned* __restrict__ ovfflag,
    unsigned* __restrict__ entries, float* __restrict__ out)
{
    int idx  = blockIdx.x * 256 + threadIdx.x;   // exact grid
    int lane = threadIdx.x & 63;
    float2 f = reinterpret_cast<const float2*>(flow)[idx];
    int sx = idx & (W - 1);
    int sy = (idx >> 9) & (H - 1);
    int b  = idx >> 18;

    float xd = (float)sx + f.x;
    float yd = (float)sy + f.y;
    float xff = floorf(xd), yff = floorf(yd);
    bool valid = (xff >= 0.0f && yff >= 0.0f &&
                  xff <= (float)(W - 2) && yff <= (float)(H - 2));
    int xf = valid ? (int)xff : 0;
    int yf = valid ? (int)yff : 0;
    float ax = xd - xff, ay = yd - yff;

    int s = sy * W + sx;
    int d = yf * W + xf;
    unsigned ax14 = min((unsigned)(ax * 16384.0f), 16383u);
    unsigned ay14 = min((unsigned)(ay * 16384.0f), 16383u);
    unsigned meta1 = (unsigned)d | (ax14 << 18);
    unsigned ay18  = ay14 << 18;

    unsigned vw[8];
    if (valid) {
        const float* p = im0 + (size_t)b * C * HW + s;
        #pragma unroll
        for (int c = 0; c < 8; ++c) {
            float v0 = p[(size_t)(2 * c)     * HW];
            float v1 = p[(size_t)(2 * c + 1) * HW];
            vw[c] = f2bf(v0) | (f2bf(v1) << 16);
        }
    } else {
        #pragma unroll
        for (int c = 0; c < 8; ++c) vw[c] = 0;
    }

    int txf = xf >> 5, txc = (xf + 1) >> 5;
    int tyf = yf >> 5, tyc = (yf + 1) >> 5;
    bool spx = (txc != txf), spy = (tyc != tyf);
    int binb = b * (TYN * TX);

    unsigned m0 = 1u | (spx ? 0u : 2u) | (spy ? 0u : 4u) | ((!spx && !spy) ? 8u : 0u);
    unsigned m1 = 2u | (spy ? 0u : 8u);
    unsigned m2 = 4u | (spx ? 0u : 8u);
    unsigned m3 = 8u;

    unsigned ovf = 0;
    #pragma unroll
    for (int k = 0; k < 4; ++k) {
        bool want; int bin; unsigned mk;
        if (k == 0)      { want = valid;               bin = binb + tyf * TX + txf; mk = m0; }
        else if (k == 1) { want = valid && spx;        bin = binb + tyf * TX + txc; mk = m1; }
        else if (k == 2) { want = valid && spy;        bin = binb + tyc * TX + txf; mk = m2; }
        else             { want = valid && spx && spy; bin = binb + tyc * TX + txc; mk = m3; }

        unsigned slot = agg_slot(want, bin, cnt, lane);
        if (want) {
            if (slot < CAP) {
                unsigned* rec = entries + ((size_t)bin * CAP + slot) * REC;
                uint2* r2 = reinterpret_cast<uint2*>(rec);
                r2[0] = make_uint2(meta1, mk | ay18);
                r2[1] = make_uint2(vw[0], vw[1]);
                r2[2] = make_uint2(vw[2], vw[3]);
                r2[3] = make_uint2(vw[4], vw[5]);
                r2[4] = make_uint2(vw[6], vw[7]);
            } else {
                ovf |= mk;
            }
        }
    }

    if (ovf) {  // statistically never
        atomicOr(ovfflag, 1u);
        float u0 = (1.f - ax) * (1.f - ay), u1 = ax * (1.f - ay);
        float u2 = (1.f - ax) * ay,         u3 = ax * ay;
        direct_splat(im0, out, b, s, xf, yf, u0, u1, u2, u3, ovf);
    }
}

// Phase 2: scatter->gather inversion in LDS. No value atomics:
// stage records, build per-cell contributor lists (counter atomics only),
// then each thread register-accumulates its cells and stores coalesced.
__global__ __launch_bounds__(256) void accum_gather_kernel(
    const unsigned* __restrict__ cnt_g, const unsigned* __restrict__ ovfflag,
    const unsigned* __restrict__ entries, float* __restrict__ out)
{
    __shared__ unsigned evals[CAP][9];        // [0..7]=bf16x2 vals, [8]=ax14|ay14<<14 (stride 9: conflict-free)
    __shared__ unsigned cnt_s[TS * TS];       // count -> cursor -> end
    __shared__ unsigned short offs_s[TS * TS];
    __shared__ unsigned short ids[4 * CAP];   // entry id (11b) | corner (2b)
    __shared__ unsigned wscan[4];

    const int bin = blockIdx.x;
    const int tid = threadIdx.x;
    const int lane = tid & 63;
    const int wv   = tid >> 6;
    const int b  = bin >> 8;
    const int ty = (bin >> 4) & 15;
    const int tx = bin & 15;
    const int y0 = ty * TS, x0 = tx * TS;

    #pragma unroll
    for (int j = 0; j < 4; ++j) cnt_s[tid + 256 * j] = 0u;
    __syncthreads();

    const int n = min((int)cnt_g[bin * CSTR], CAP);

    // --- B: stage records into LDS + count corner contributions per cell ---
    unsigned dm[5];   // (lx+1) | (ly+1)<<6 | mask<<12  (static-indexed, full unroll)
    #pragma unroll
    for (int it = 0; it < 5; ++it) {
        int i = it * 256 + tid;
        unsigned dmv = 0;
        if (i < n) {
            const uint2* rec = reinterpret_cast<const uint2*>(
                entries + ((size_t)bin * CAP + i) * REC);
            uint2 m  = rec[0];
            uint2 q0 = rec[1], q1 = rec[2], q2 = rec[3], q3 = rec[4];
            int d = (int)(m.x & 0x3FFFFu);
            unsigned mask = m.y & 15u;
            unsigned ax14 = m.x >> 18, ay14 = m.y >> 18;
            int xf = d & (W - 1), yf = d >> 9;
            int lx = xf - x0 + 1;   // 0..32
            int ly = yf - y0 + 1;   // 0..32
            dmv = (unsigned)lx | ((unsigned)ly << 6) | (mask << 12);
            evals[i][0] = q0.x; evals[i][1] = q0.y;
            evals[i][2] = q1.x; evals[i][3] = q1.y;
            evals[i][4] = q2.x; evals[i][5] = q2.y;
            evals[i][6] = q3.x; evals[i][7] = q3.y;
            evals[i][8] = ax14 | (ay14 << 14);
            #pragma unroll
            for (int corner = 0; corner < 4; ++corner) {
                if (mask & (1u << corner)) {
                    int cell = (ly - 1 + (corner >> 1)) * TS + (lx - 1 + (corner & 1));
                    atomicAdd(&cnt_s[cell], 1u);
                }
            }
        }
        dm[it] = dmv;
    }
    __syncthreads();

    // --- C: block prefix scan of 1024 cell counts (4 cells/thread) ---
    unsigned c0 = cnt_s[4 * tid], c1 = cnt_s[4 * tid + 1];
    unsigned c2 = cnt_s[4 * tid + 2], c3 = cnt_s[4 * tid + 3];
    unsigned s4 = c0 + c1 + c2 + c3;
    unsigned ps = s4;
    #pragma unroll
    for (int dlt = 1; dlt < 64; dlt <<= 1) {
        unsigned o = __shfl_up(ps, dlt, 64);
        if (lane >= dlt) ps += o;
    }
    if (lane == 63) wscan[wv] = ps;
    __syncthreads();
    if (tid == 0) {
        unsigned a = 0;
        #pragma unroll
        for (int w_ = 0; w_ < 4; ++w_) { unsigned t_ = wscan[w_]; wscan[w_] = a; a += t_; }
    }
    __syncthreads();
    unsigned base = wscan[wv] + ps - s4;
    offs_s[4 * tid]     = (unsigned short)base;              cnt_s[4 * tid]     = base;
    offs_s[4 * tid + 1] = (unsigned short)(base + c0);       cnt_s[4 * tid + 1] = base + c0;
    offs_s[4 * tid + 2] = (unsigned short)(base + c0 + c1);  cnt_s[4 * tid + 2] = base + c0 + c1;
    offs_s[4 * tid + 3] = (unsigned short)(base + c0 + c1 + c2); cnt_s[4 * tid + 3] = base + c0 + c1 + c2;
    __syncthreads();

    // --- D: place contributor ids (cursor atomics; cnt_s ends at range end) ---
    #pragma unroll
    for (int it = 0; it < 5; ++it) {
        int i = it * 256 + tid;
        unsigned dmv = dm[it];
        unsigned mask = dmv >> 12;
        if (i < n && mask) {
            int lx = (int)(dmv & 63u), ly = (int)((dmv >> 6) & 63u);
            #pragma unroll
            for (int corner = 0; corner < 4; ++corner) {
                if (mask & (1u << corner)) {
                    int cell = (ly - 1 + (corner >> 1)) * TS + (lx - 1 + (corner & 1));
                    unsigned slot = atomicAdd(&cnt_s[cell], 1u);
                    ids[slot] = (unsigned short)((unsigned)i | ((unsigned)corner << 11));
                }
            }
        }
    }
    __syncthreads();

    // --- E: gather per cell, register accumulate, coalesced store ---
    const bool rmw = (*ovfflag != 0u);
    size_t outb = (size_t)b * C * HW;
    #pragma unroll
    for (int j = 0; j < 4; ++j) {
        int cell = tid + 256 * j;
        int cy = cell >> 5, cx = cell & 31;
        float acc[16];
        #pragma unroll
        for (int c = 0; c < 16; ++c) acc[c] = 0.0f;

        int k0 = (int)offs_s[cell];
        int k1 = (int)cnt_s[cell];
        for (int k = k0; k < k1; ++k) {
            unsigned id2 = ids[k];
            unsigned e = id2 & 0x7FFu;
            unsigned corner = id2 >> 11;
            unsigned wt = evals[e][8];
            float ax = (float)(wt & 0x3FFFu) * (1.0f / 16384.0f);
            float ay = (float)((wt >> 14) & 0x3FFFu) * (1.0f / 16384.0f);
            float fx = (corner & 1u) ? ax : 1.0f - ax;
            float fy = (corner & 2u) ? ay : 1.0f - ay;
            float wgt = fx * fy;
            #pragma unroll
            for (int cp = 0; cp < 8; ++cp) {
                unsigned vwv = evals[e][cp];
                acc[2 * cp]     += wgt * bf_lo(vwv);
                acc[2 * cp + 1] += wgt * bf_hi(vwv);
            }
        }

        float* op0 = out + outb + (size_t)(y0 + cy) * W + (x0 + cx);
        if (rmw) {
            #pragma unroll
            for (int c = 0; c < 16; ++c) { float* op = op0 + (size_t)c * HW; *op = *op + acc[c]; }
        } else {
            #pragma unroll
            for (int c = 0; c < 16; ++c) { float* op = op0 + (size_t)c * HW; *op = acc[c]; }
        }
    }
}

// =================== FALLBACK 1: wide path (11 MB ws) ===================

__global__ __launch_bounds__(256) void bin_wide_kernel(
    const float* __restrict__ flow, const float* __restrict__ im0,
    unsigned* __restrict__ cnt, unsigned* __restrict__ entries,
    float* __restrict__ out)
{
    int idx  = blockIdx.x * 256 + threadIdx.x;
    int lane = threadIdx.x & 63;
    float2 f = reinterpret_cast<const float2*>(flow)[idx];
    int sx = idx & (W - 1);
    int sy = (idx >> 9) & (H - 1);
    int b  = idx >> 18;

    float xd = (float)sx + f.x;
    float yd = (float)sy + f.y;
    float xff = floorf(xd), yff = floorf(yd);
    bool valid = (xff >= 0.0f && yff >= 0.0f &&
                  xff <= (float)(W - 2) && yff <= (float)(H - 2));
    int xf = valid ? (int)xff : 0;
    int yf = valid ? (int)yff : 0;
    float ax = xd - xff, ay = yd - yff;

    int s = sy * W + sx;
    int d = yf * W + xf;
    unsigned ax14 = min((unsigned)(ax * 16384.0f), 16383u);
    unsigned ay14 = min((unsigned)(ay * 16384.0f), 16383u);
    unsigned w0 = (unsigned)s | (ax14 << 18);
    unsigned w1 = (unsigned)d | (ay14 << 18);

    int txf = xf >> 5, txc = (xf + 1) >> 5;
    int tyf = yf >> 5, tyc = (yf + 1) >> 5;
    bool spx = (txc != txf), spy = (tyc != tyf);
    int binb = b * (TYN * TX);

    unsigned m0 = 1u | (spx ? 0u : 2u) | (spy ? 0u : 4u) | ((!spx && !spy) ? 8u : 0u);
    unsigned m1 = 2u | (spy ? 0u : 8u);
    unsigned m2 = 4u | (spx ? 0u : 8u);
    unsigned m3 = 8u;

    unsigned ovf = 0;
    #pragma unroll
    for (int k = 0; k < 4; ++k) {
        bool want; int bin; unsigned mk;
        if (k == 0)      { want = valid;               bin = binb + tyf * TX + txf; mk = m0; }
        else if (k == 1) { want = valid && spx;        bin = binb + tyf * TX + txc; mk = m1; }
        else if (k == 2) { want = valid && spy;        bin = binb + tyc * TX + txf; mk = m2; }
        else             { want = valid && spx && spy; bin = binb + tyc * TX + txc; mk = m3; }
        unsigned slot = agg_slot(want, bin, cnt, lane);
        if (want) {
            if (slot < CAP)
                reinterpret_cast<uint2*>(entries)[(size_t)bin * CAP + slot] =
                    make_uint2(w0, w1);
            else
                ovf |= mk;
        }
    }
    if (ovf) {
        float u0 = (1.f - ax) * (1.f - ay), u1 = ax * (1.f - ay);
        float u2 = (1.f - ax) * ay,         u3 = ax * ay;
        direct_splat(im0, out, b, s, xf, yf, u0, u1, u2, u3, ovf);
    }
}

__global__ __launch_bounds__(256) void accum_wide_kernel(
    const float* __restrict__ im0,
    const unsigned* __restrict__ cnt, const unsigned* __restrict__ entries,
    float* __restrict__ out)
{
    __shared__ float acc[CPB * TS * TS];
    const int bin = blockIdx.x;
    const int c0  = blockIdx.y * CPB;
    const int tid = threadIdx.x;
    const int b  = bin >> 8;
    const int ty = (bin >> 4) & 15;
    const int tx = bin & 15;
    const int y0 = ty * TS, x0 = tx * TS;

    for (int i = tid; i < CPB * TS * TS; i += 256) acc[i] = 0.0f;
    __syncthreads();

    const int n = min((int)cnt[bin * CSTR], CAP);
    const float* im0b = im0 + (size_t)b * C * HW + (size_t)c0 * HW;

    for (int i = tid; i < n; i += 256) {
        uint2 e = reinterpret_cast<const uint2*>(entries)[(size_t)bin * CAP + i];
        int s = (int)(e.x & 0x3FFFFu);
        int d = (int)(e.y & 0x3FFFFu);
        float ax = (float)(e.x >> 18) * (1.0f / 16384.0f);
        float ay = (float)(e.y >> 18) * (1.0f / 16384.0f);
        int xf = d & (W - 1), yf = d >> 9;
        int lx = xf - x0, ly = yf - y0;
        float wnw = (1.f - ax) * (1.f - ay), wne = ax * (1.f - ay);
        float wsw = (1.f - ax) * ay,         wse = ax * ay;
        bool p0 = (unsigned)lx < (unsigned)TS && (unsigned)ly < (unsigned)TS;
        bool p1 = (unsigned)(lx + 1) < (unsigned)TS && (unsigned)ly < (unsigned)TS;
        bool p2 = (unsigned)lx < (unsigned)TS && (unsigned)(ly + 1) < (unsigned)TS;
        bool p3 = (unsigned)(lx + 1) < (unsigned)TS && (unsigned)(ly + 1) < (unsigned)TS;
        int l0 = ly * TS + lx;

        float v[CPB];
        #pragma unroll
        for (int c = 0; c < CPB; ++c) v[c] = im0b[(size_t)c * HW + s];
        #pragma unroll
        for (int c = 0; c < CPB; ++c) {
            float* a = acc + c * (TS * TS);
            if (p0) fadd(&a[l0],          v[c] * wnw);
            if (p1) fadd(&a[l0 + 1],      v[c] * wne);
            if (p2) fadd(&a[l0 + TS],     v[c] * wsw);
            if (p3) fadd(&a[l0 + TS + 1], v[c] * wse);
        }
    }
    __syncthreads();

    size_t outb = (size_t)b * C * HW + (size_t)c0 * HW;
    for (int i = tid; i < (CPB * TS * TS) / 4; i += 256) {
        int c   = i >> 8;
        int rem = i & 255;
        int y   = rem >> 3;
        int x4  = (rem & 7) * 4;
        float4 a = *reinterpret_cast<const float4*>(&acc[c * TS * TS + y * TS + x4]);
        float* op = out + outb + (size_t)c * HW + (size_t)(y0 + y) * W + (x0 + x4);
        float4 cur = *reinterpret_cast<float4*>(op);
        cur.x += a.x; cur.y += a.y; cur.z += a.z; cur.w += a.w;
        *reinterpret_cast<float4*>(op) = cur;
    }
}

// =================== FALLBACK 2: naive direct-atomic ===================
__global__ __launch_bounds__(256) void warp_naive_kernel(
    const float* __restrict__ im0, const float* __restrict__ flow,
    float* __restrict__ out)
{
    int idx = blockIdx.x * 256 + threadIdx.x;
    if (idx >= B * HW) return;
    int w = idx & (W - 1);
    int h = (idx >> 9) & (H - 1);
    int b = idx >> 18;
    float2 f = reinterpret_cast<const float2*>(flow)[idx];
    float xd = (float)w + f.x, yd = (float)h + f.y;
    float xff = floorf(xd), yff = floorf(yd);
    if (!(xff >= 0.0f && yff >= 0.0f &&
          xff <= (float)(W - 2) && yff <= (float)(H - 2))) return;
    int xf = (int)xff, yf = (int)yff;
    float ax = xd - xff, ay = yd - yff;
    float w0 = (1.f - ax) * (1.f - ay), w1 = ax * (1.f - ay);
    float w2 = (1.f - ax) * ay,         w3 = ax * ay;
    direct_splat(im0, out, b, h * W + w, xf, yf, w0, w1, w2, w3, 15u);
}

extern "C" void kernel_launch(void* const* d_in, const int* in_sizes, int n_in,
                              void* d_out, int out_size, void* d_ws, size_t ws_size,
                              hipStream_t stream) {
    const float* im0  = (const float*)d_in[0];
    const float* flow = (const float*)d_in[1];
    float* out = (float*)d_out;

    hipMemsetAsync(out, 0, (size_t)out_size * sizeof(float), stream);

    // ws layout: cnt[NBINS*CSTR] u32 | ovfflag (64B pad) | entries
    constexpr size_t hdr_words = (size_t)NBINS * CSTR + 16;
    constexpr size_t need_hdr  = hdr_words * 4;
    constexpr size_t need_vals = need_hdr + (size_t)NBINS * CAP * REC * 4;  // ~52.5 MB
    constexpr size_t need_wide = need_hdr + (size_t)NBINS * CAP * 8;        // ~10.6 MB
    constexpr int total = B * HW;

    if (ws_size < need_wide) {
        warp_naive_kernel<<<(total + 255) / 256, 256, 0, stream>>>(im0, flow, out);
        return;
    }

    unsigned* cnt = (unsigned*)d_ws;
    unsigned* ovfflag = cnt + (size_t)NBINS * CSTR;
    unsigned* entries = cnt + hdr_words;
    hipMemsetAsync(cnt, 0, need_hdr, stream);

    if (ws_size >= need_vals) {
        bin_vals_kernel<<<total / 256, 256, 0, stream>>>(flow, im0, cnt, ovfflag, entries, out);
        accum_gather_kernel<<<NBINS, 256, 0, stream>>>(cnt, ovfflag, entries, out);
    } else {
        bin_wide_kernel<<<total / 256, 256, 0, stream>>>(flow, im0, cnt, entries, out);
        dim3 agrid(NBINS, C / CPB);
        accum_wide_kernel<<<agrid, 256, 0, stream>>>(im0, cnt, entries, out);
    }
}

// Round 8
// 71.036 us; speedup vs baseline: 5.7827x; 1.1739x over previous
//
#include <hip/hip_runtime.h>

constexpr int B = 4, C = 16, H = 512, W = 512;
constexpr int HW = H * W;
constexpr int TS = 32, TX = 16, TYN = 16;
constexpr int NBINS = B * TYN * TX;   // 1024
constexpr int CAP   = 1280;           // slots per bin (expected max ~1230)
constexpr int CSTR  = 16;             // counter stride in u32 -> 64B per counter
constexpr int REC   = 10;             // u32 words per value-record (40 B)
constexpr int OVF_CAP = 65536;        // overflow side-list entries
constexpr int CPB   = 8;              // channels per block (fallback wide path)

__device__ __forceinline__ void fadd(float* p, float v) { unsafeAtomicAdd(p, v); }

// round-to-nearest-even f32 -> bf16 (upper 16 bits)
__device__ __forceinline__ unsigned f2bf(float x) {
    unsigned u = __float_as_uint(x);
    return (u + 0x7FFFu + ((u >> 16) & 1u)) >> 16;
}
__device__ __forceinline__ float bf_lo(unsigned w) { return __uint_as_float(w << 16); }
__device__ __forceinline__ float bf_hi(unsigned w) { return __uint_as_float(w & 0xFFFF0000u); }

// ---- direct global-atomic splat (fixup / fallback paths) ----
__device__ __forceinline__ void direct_splat(
    const float* __restrict__ im0, float* __restrict__ out,
    int b, int s, int xf, int yf,
    float w0, float w1, float w2, float w3, unsigned mask)
{
    size_t base = (size_t)b * C * HW;
    int d00 = yf * W + xf;
    for (int c = 0; c < C; ++c) {
        float v = im0[base + (size_t)c * HW + s];
        float* o = out + base + (size_t)c * HW + d00;
        if (mask & 1u) fadd(o,         v * w0);
        if (mask & 2u) fadd(o + 1,     v * w1);
        if (mask & 4u) fadd(o + W,     v * w2);
        if (mask & 8u) fadd(o + W + 1, v * w3);
    }
}

__device__ __forceinline__ void write_rec(
    unsigned* __restrict__ entries, int bin, unsigned slot,
    unsigned meta1, unsigned meta2, const unsigned vw[8])
{
    unsigned* rec = entries + ((size_t)bin * CAP + slot) * REC;
    uint2* r2 = reinterpret_cast<uint2*>(rec);
    r2[0] = make_uint2(meta1, meta2);
    r2[1] = make_uint2(vw[0], vw[1]);
    r2[2] = make_uint2(vw[2], vw[3]);
    r2[3] = make_uint2(vw[4], vw[5]);
    r2[4] = make_uint2(vw[6], vw[7]);
}

// =================== PRIMARY PATH ===================

// Phase 1: block-aggregated binning. LDS count -> ONE parallel global
// reserve per (block, nonzero bin) -> LDS-cursor placement. No serialized
// wave ballot loops, no returning-global-atomic dependency chains.
__global__ __launch_bounds__(256) void bin2_kernel(
    const float* __restrict__ flow, const float* __restrict__ im0,
    unsigned* __restrict__ cnt, unsigned* __restrict__ ovf_cnt,
    unsigned* __restrict__ ovf_list, unsigned* __restrict__ entries)
{
    __shared__ unsigned lcnt[NBINS];    // per-block count, then cursor
    __shared__ unsigned gbase[NBINS];   // block's reserved global base
    const int tid = threadIdx.x;

    #pragma unroll
    for (int j = 0; j < NBINS / 256; ++j) lcnt[tid + 256 * j] = 0u;
    __syncthreads();

    const int idx = blockIdx.x * 256 + tid;   // exact grid
    float2 f = reinterpret_cast<const float2*>(flow)[idx];
    int sx = idx & (W - 1);
    int sy = (idx >> 9) & (H - 1);
    int b  = idx >> 18;

    float xd = (float)sx + f.x;
    float yd = (float)sy + f.y;
    float xff = floorf(xd), yff = floorf(yd);
    bool valid = (xff >= 0.0f && yff >= 0.0f &&
                  xff <= (float)(W - 2) && yff <= (float)(H - 2));
    int xf = valid ? (int)xff : 0;
    int yf = valid ? (int)yff : 0;
    float ax = xd - xff, ay = yd - yff;

    int s = sy * W + sx;
    int d = yf * W + xf;
    unsigned ax14 = min((unsigned)(ax * 16384.0f), 16383u);
    unsigned ay14 = min((unsigned)(ay * 16384.0f), 16383u);
    unsigned meta1 = (unsigned)d | (ax14 << 18);
    unsigned ay18  = ay14 << 18;

    unsigned vw[8];
    if (valid) {
        const float* p = im0 + (size_t)b * C * HW + s;
        #pragma unroll
        for (int c = 0; c < 8; ++c) {
            float v0 = p[(size_t)(2 * c)     * HW];
            float v1 = p[(size_t)(2 * c + 1) * HW];
            vw[c] = f2bf(v0) | (f2bf(v1) << 16);
        }
    } else {
        #pragma unroll
        for (int c = 0; c < 8; ++c) vw[c] = 0;
    }

    int txf = xf >> 5, txc = (xf + 1) >> 5;
    int tyf = yf >> 5, tyc = (yf + 1) >> 5;
    bool spx = (txc != txf), spy = (tyc != tyf);
    int binb = b * (TYN * TX);

    const bool w0_ = valid, w1_ = valid && spx, w2_ = valid && spy,
               w3_ = valid && spx && spy;
    const int b0 = binb + tyf * TX + txf, b1 = binb + tyf * TX + txc;
    const int b2 = binb + tyc * TX + txf, b3 = binb + tyc * TX + txc;
    const unsigned m0 = 1u | (spx ? 0u : 2u) | (spy ? 0u : 4u) | ((!spx && !spy) ? 8u : 0u);
    const unsigned m1 = 2u | (spy ? 0u : 8u);
    const unsigned m2 = 4u | (spx ? 0u : 8u);
    const unsigned m3 = 8u;

    // count phase (non-returning LDS atomics — fast issue, no dependency)
    if (w0_) atomicAdd(&lcnt[b0], 1u);
    if (w1_) atomicAdd(&lcnt[b1], 1u);
    if (w2_) atomicAdd(&lcnt[b2], 1u);
    if (w3_) atomicAdd(&lcnt[b3], 1u);
    __syncthreads();

    // global reserve: ~60 nonzero bins per block, all atomics issued in
    // parallel by distinct threads -> one round-trip, not a serial chain
    #pragma unroll
    for (int j = 0; j < NBINS / 256; ++j) {
        int bn = tid + 256 * j;
        unsigned c = lcnt[bn];
        unsigned gb = 0;
        if (c) gb = atomicAdd(&cnt[bn * CSTR], c);
        gbase[bn] = gb;
        lcnt[bn] = 0u;      // reuse as cursor
    }
    __syncthreads();

    // place phase (LDS returning atomics ~fast; <=4 per thread)
    unsigned ovfmask = 0;
    if (w0_) { unsigned r = atomicAdd(&lcnt[b0], 1u); unsigned sl = gbase[b0] + r;
               if (sl < CAP) write_rec(entries, b0, sl, meta1, m0 | ay18, vw); else ovfmask |= m0; }
    if (w1_) { unsigned r = atomicAdd(&lcnt[b1], 1u); unsigned sl = gbase[b1] + r;
               if (sl < CAP) write_rec(entries, b1, sl, meta1, m1 | ay18, vw); else ovfmask |= m1; }
    if (w2_) { unsigned r = atomicAdd(&lcnt[b2], 1u); unsigned sl = gbase[b2] + r;
               if (sl < CAP) write_rec(entries, b2, sl, meta1, m2 | ay18, vw); else ovfmask |= m2; }
    if (w3_) { unsigned r = atomicAdd(&lcnt[b3], 1u); unsigned sl = gbase[b3] + r;
               if (sl < CAP) write_rec(entries, b3, sl, meta1, m3 | ay18, vw); else ovfmask |= m3; }

    if (ovfmask) {   // statistically never: queue for post-accum fixup
        unsigned o = atomicAdd(ovf_cnt, 1u);
        if (o < OVF_CAP)
            ovf_list[o] = ((unsigned)b << 22) | ((unsigned)s << 4) | ovfmask;
    }
}

// Phase 2: scatter->gather inversion in LDS (no value atomics), plain
// coalesced stores — writes EVERY output element, so no out-memset needed.
__global__ __launch_bounds__(256) void accum_gather_kernel(
    const unsigned* __restrict__ cnt_g, const unsigned* __restrict__ entries,
    float* __restrict__ out)
{
    __shared__ unsigned evals[CAP][9];        // [0..7]=bf16x2 vals, [8]=ax14|ay14<<14
    __shared__ unsigned cnt_s[TS * TS];       // count -> cursor -> end
    __shared__ unsigned short offs_s[TS * TS];
    __shared__ unsigned short ids[4 * CAP];   // entry id (11b) | corner (2b)
    __shared__ unsigned wscan[4];

    const int bin = blockIdx.x;
    const int tid = threadIdx.x;
    const int lane = tid & 63;
    const int wv   = tid >> 6;
    const int b  = bin >> 8;
    const int ty = (bin >> 4) & 15;
    const int tx = bin & 15;
    const int y0 = ty * TS, x0 = tx * TS;

    #pragma unroll
    for (int j = 0; j < 4; ++j) cnt_s[tid + 256 * j] = 0u;
    __syncthreads();

    const int n = min((int)cnt_g[bin * CSTR], CAP);

    // --- stage records into LDS + count corner contributions per cell ---
    unsigned dm[5];
    #pragma unroll
    for (int it = 0; it < 5; ++it) {
        int i = it * 256 + tid;
        unsigned dmv = 0;
        if (i < n) {
            const uint2* rec = reinterpret_cast<const uint2*>(
                entries + ((size_t)bin * CAP + i) * REC);
            uint2 m  = rec[0];
            uint2 q0 = rec[1], q1 = rec[2], q2 = rec[3], q3 = rec[4];
            int d = (int)(m.x & 0x3FFFFu);
            unsigned mask = m.y & 15u;
            unsigned ax14 = m.x >> 18, ay14 = m.y >> 18;
            int xf = d & (W - 1), yf = d >> 9;
            int lx = xf - x0 + 1;   // 0..32
            int ly = yf - y0 + 1;   // 0..32
            dmv = (unsigned)lx | ((unsigned)ly << 6) | (mask << 12);
            evals[i][0] = q0.x; evals[i][1] = q0.y;
            evals[i][2] = q1.x; evals[i][3] = q1.y;
            evals[i][4] = q2.x; evals[i][5] = q2.y;
            evals[i][6] = q3.x; evals[i][7] = q3.y;
            evals[i][8] = ax14 | (ay14 << 14);
            #pragma unroll
            for (int corner = 0; corner < 4; ++corner) {
                if (mask & (1u << corner)) {
                    int cell = (ly - 1 + (corner >> 1)) * TS + (lx - 1 + (corner & 1));
                    atomicAdd(&cnt_s[cell], 1u);
                }
            }
        }
        dm[it] = dmv;
    }
    __syncthreads();

    // --- block prefix scan of 1024 cell counts (4 cells/thread) ---
    unsigned c0 = cnt_s[4 * tid], c1 = cnt_s[4 * tid + 1];
    unsigned c2 = cnt_s[4 * tid + 2], c3 = cnt_s[4 * tid + 3];
    unsigned s4 = c0 + c1 + c2 + c3;
    unsigned ps = s4;
    #pragma unroll
    for (int dlt = 1; dlt < 64; dlt <<= 1) {
        unsigned o = __shfl_up(ps, dlt, 64);
        if (lane >= dlt) ps += o;
    }
    if (lane == 63) wscan[wv] = ps;
    __syncthreads();
    if (tid == 0) {
        unsigned a = 0;
        #pragma unroll
        for (int w_ = 0; w_ < 4; ++w_) { unsigned t_ = wscan[w_]; wscan[w_] = a; a += t_; }
    }
    __syncthreads();
    unsigned base = wscan[wv] + ps - s4;
    offs_s[4 * tid]     = (unsigned short)base;                  cnt_s[4 * tid]     = base;
    offs_s[4 * tid + 1] = (unsigned short)(base + c0);           cnt_s[4 * tid + 1] = base + c0;
    offs_s[4 * tid + 2] = (unsigned short)(base + c0 + c1);      cnt_s[4 * tid + 2] = base + c0 + c1;
    offs_s[4 * tid + 3] = (unsigned short)(base + c0 + c1 + c2); cnt_s[4 * tid + 3] = base + c0 + c1 + c2;
    __syncthreads();

    // --- place contributor ids (LDS cursor atomics) ---
    #pragma unroll
    for (int it = 0; it < 5; ++it) {
        int i = it * 256 + tid;
        unsigned dmv = dm[it];
        unsigned mask = dmv >> 12;
        if (i < n && mask) {
            int lx = (int)(dmv & 63u), ly = (int)((dmv >> 6) & 63u);
            #pragma unroll
            for (int corner = 0; corner < 4; ++corner) {
                if (mask & (1u << corner)) {
                    int cell = (ly - 1 + (corner >> 1)) * TS + (lx - 1 + (corner & 1));
                    unsigned slot = atomicAdd(&cnt_s[cell], 1u);
                    ids[slot] = (unsigned short)((unsigned)i | ((unsigned)corner << 11));
                }
            }
        }
    }
    __syncthreads();

    // --- gather per cell, register accumulate, coalesced plain store ---
    size_t outb = (size_t)b * C * HW;
    #pragma unroll
    for (int j = 0; j < 4; ++j) {
        int cell = tid + 256 * j;
        int cy = cell >> 5, cx = cell & 31;
        float acc[16];
        #pragma unroll
        for (int c = 0; c < 16; ++c) acc[c] = 0.0f;

        int k0 = (int)offs_s[cell];
        int k1 = (int)cnt_s[cell];
        for (int k = k0; k < k1; ++k) {
            unsigned id2 = ids[k];
            unsigned e = id2 & 0x7FFu;
            unsigned corner = id2 >> 11;
            unsigned wt = evals[e][8];
            float ax = (float)(wt & 0x3FFFu) * (1.0f / 16384.0f);
            float ay = (float)((wt >> 14) & 0x3FFFu) * (1.0f / 16384.0f);
            float fx = (corner & 1u) ? ax : 1.0f - ax;
            float fy = (corner & 2u) ? ay : 1.0f - ay;
            float wgt = fx * fy;
            #pragma unroll
            for (int cp = 0; cp < 8; ++cp) {
                unsigned vwv = evals[e][cp];
                acc[2 * cp]     += wgt * bf_lo(vwv);
                acc[2 * cp + 1] += wgt * bf_hi(vwv);
            }
        }

        float* op0 = out + outb + (size_t)(y0 + cy) * W + (x0 + cx);
        #pragma unroll
        for (int c = 0; c < 16; ++c) op0[(size_t)c * HW] = acc[c];
    }
}

// Phase 3: process overflow side-list (usually empty) AFTER plain stores.
__global__ __launch_bounds__(256) void fixup_kernel(
    const float* __restrict__ flow, const float* __restrict__ im0,
    const unsigned* __restrict__ ovf_cnt, const unsigned* __restrict__ ovf_list,
    float* __restrict__ out)
{
    unsigned n = min(*ovf_cnt, (unsigned)OVF_CAP);
    for (unsigned i = blockIdx.x * 256 + threadIdx.x; i < n; i += gridDim.x * 256) {
        unsigned e = ovf_list[i];
        int b = (int)(e >> 22);
        int s = (int)((e >> 4) & 0x3FFFFu);
        unsigned mask = e & 15u;
        int sx = s & (W - 1), sy = s >> 9;
        float2 f = reinterpret_cast<const float2*>(flow)[(size_t)b * HW + s];
        float xd = (float)sx + f.x, yd = (float)sy + f.y;
        float xff = floorf(xd), yff = floorf(yd);
        int xf = (int)xff, yf = (int)yff;
        float ax = xd - xff, ay = yd - yff;
        float w0 = (1.f - ax) * (1.f - ay), w1 = ax * (1.f - ay);
        float w2 = (1.f - ax) * ay,         w3 = ax * ay;
        direct_splat(im0, out, b, s, xf, yf, w0, w1, w2, w3, mask);
    }
}

// =================== FALLBACK 1: wide path (11 MB ws) ===================

__device__ __forceinline__ unsigned agg_slot(
    bool want, int bin, unsigned* __restrict__ cnt, int lane)
{
    unsigned slot = 0xFFFFFFFFu;
    unsigned long long act = __ballot(want);
    while (act) {
        int leader = (int)__builtin_ctzll(act);
        int lbin = __shfl(bin, leader);
        bool mine = want && (bin == lbin);
        unsigned long long grp = __ballot(mine);
        unsigned base = 0;
        if (lane == leader)
            base = atomicAdd(&cnt[(unsigned)lbin * CSTR], (unsigned)__popcll(grp));
        base = (unsigned)__shfl((int)base, leader);
        if (mine)
            slot = base + (unsigned)__popcll(grp & ((1ull << lane) - 1ull));
        act &= ~grp;
    }
    return slot;
}

__global__ __launch_bounds__(256) void bin_wide_kernel(
    const float* __restrict__ flow, const float* __restrict__ im0,
    unsigned* __restrict__ cnt, unsigned* __restrict__ entries,
    float* __restrict__ out)
{
    int idx  = blockIdx.x * 256 + threadIdx.x;
    int lane = threadIdx.x & 63;
    float2 f = reinterpret_cast<const float2*>(flow)[idx];
    int sx = idx & (W - 1);
    int sy = (idx >> 9) & (H - 1);
    int b  = idx >> 18;

    float xd = (float)sx + f.x;
    float yd = (float)sy + f.y;
    float xff = floorf(xd), yff = floorf(yd);
    bool valid = (xff >= 0.0f && yff >= 0.0f &&
                  xff <= (float)(W - 2) && yff <= (float)(H - 2));
    int xf = valid ? (int)xff : 0;
    int yf = valid ? (int)yff : 0;
    float ax = xd - xff, ay = yd - yff;

    int s = sy * W + sx;
    int d = yf * W + xf;
    unsigned ax14 = min((unsigned)(ax * 16384.0f), 16383u);
    unsigned ay14 = min((unsigned)(ay * 16384.0f), 16383u);
    unsigned w0 = (unsigned)s | (ax14 << 18);
    unsigned w1 = (unsigned)d | (ay14 << 18);

    int txf = xf >> 5, txc = (xf + 1) >> 5;
    int tyf = yf >> 5, tyc = (yf + 1) >> 5;
    bool spx = (txc != txf), spy = (tyc != tyf);
    int binb = b * (TYN * TX);

    unsigned m0 = 1u | (spx ? 0u : 2u) | (spy ? 0u : 4u) | ((!spx && !spy) ? 8u : 0u);
    unsigned m1 = 2u | (spy ? 0u : 8u);
    unsigned m2 = 4u | (spx ? 0u : 8u);
    unsigned m3 = 8u;

    unsigned ovf = 0;
    #pragma unroll
    for (int k = 0; k < 4; ++k) {
        bool want; int bin; unsigned mk;
        if (k == 0)      { want = valid;               bin = binb + tyf * TX + txf; mk = m0; }
        else if (k == 1) { want = valid && spx;        bin = binb + tyf * TX + txc; mk = m1; }
        else if (k == 2) { want = valid && spy;        bin = binb + tyc * TX + txf; mk = m2; }
        else             { want = valid && spx && spy; bin = binb + tyc * TX + txc; mk = m3; }
        unsigned slot = agg_slot(want, bin, cnt, lane);
        if (want) {
            if (slot < CAP)
                reinterpret_cast<uint2*>(entries)[(size_t)bin * CAP + slot] =
                    make_uint2(w0, w1);
            else
                ovf |= mk;
        }
    }
    if (ovf) {
        float u0 = (1.f - ax) * (1.f - ay), u1 = ax * (1.f - ay);
        float u2 = (1.f - ax) * ay,         u3 = ax * ay;
        direct_splat(im0, out, b, s, xf, yf, u0, u1, u2, u3, ovf);
    }
}

__global__ __launch_bounds__(256) void accum_wide_kernel(
    const float* __restrict__ im0,
    const unsigned* __restrict__ cnt, const unsigned* __restrict__ entries,
    float* __restrict__ out)
{
    __shared__ float acc[CPB * TS * TS];
    const int bin = blockIdx.x;
    const int c0  = blockIdx.y * CPB;
    const int tid = threadIdx.x;
    const int b  = bin >> 8;
    const int ty = (bin >> 4) & 15;
    const int tx = bin & 15;
    const int y0 = ty * TS, x0 = tx * TS;

    for (int i = tid; i < CPB * TS * TS; i += 256) acc[i] = 0.0f;
    __syncthreads();

    const int n = min((int)cnt[bin * CSTR], CAP);
    const float* im0b = im0 + (size_t)b * C * HW + (size_t)c0 * HW;

    for (int i = tid; i < n; i += 256) {
        uint2 e = reinterpret_cast<const uint2*>(entries)[(size_t)bin * CAP + i];
        int s = (int)(e.x & 0x3FFFFu);
        int d = (int)(e.y & 0x3FFFFu);
        float ax = (float)(e.x >> 18) * (1.0f / 16384.0f);
        float ay = (float)(e.y >> 18) * (1.0f / 16384.0f);
        int xf = d & (W - 1), yf = d >> 9;
        int lx = xf - x0, ly = yf - y0;
        float wnw = (1.f - ax) * (1.f - ay), wne = ax * (1.f - ay);
        float wsw = (1.f - ax) * ay,         wse = ax * ay;
        bool p0 = (unsigned)lx < (unsigned)TS && (unsigned)ly < (unsigned)TS;
        bool p1 = (unsigned)(lx + 1) < (unsigned)TS && (unsigned)ly < (unsigned)TS;
        bool p2 = (unsigned)lx < (unsigned)TS && (unsigned)(ly + 1) < (unsigned)TS;
        bool p3 = (unsigned)(lx + 1) < (unsigned)TS && (unsigned)(ly + 1) < (unsigned)TS;
        int l0 = ly * TS + lx;

        float v[CPB];
        #pragma unroll
        for (int c = 0; c < CPB; ++c) v[c] = im0b[(size_t)c * HW + s];
        #pragma unroll
        for (int c = 0; c < CPB; ++c) {
            float* a = acc + c * (TS * TS);
            if (p0) fadd(&a[l0],          v[c] * wnw);
            if (p1) fadd(&a[l0 + 1],      v[c] * wne);
            if (p2) fadd(&a[l0 + TS],     v[c] * wsw);
            if (p3) fadd(&a[l0 + TS + 1], v[c] * wse);
        }
    }
    __syncthreads();

    size_t outb = (size_t)b * C * HW + (size_t)c0 * HW;
    for (int i = tid; i < (CPB * TS * TS) / 4; i += 256) {
        int c   = i >> 8;
        int rem = i & 255;
        int y   = rem >> 3;
        int x4  = (rem & 7) * 4;
        float4 a = *reinterpret_cast<const float4*>(&acc[c * TS * TS + y * TS + x4]);
        float* op = out + outb + (size_t)c * HW + (size_t)(y0 + y) * W + (x0 + x4);
        float4 cur = *reinterpret_cast<float4*>(op);
        cur.x += a.x; cur.y += a.y; cur.z += a.z; cur.w += a.w;
        *reinterpret_cast<float4*>(op) = cur;
    }
}

// =================== FALLBACK 2: naive direct-atomic ===================
__global__ __launch_bounds__(256) void warp_naive_kernel(
    const float* __restrict__ im0, const float* __restrict__ flow,
    float* __restrict__ out)
{
    int idx = blockIdx.x * 256 + threadIdx.x;
    if (idx >= B * HW) return;
    int w = idx & (W - 1);
    int h = (idx >> 9) & (H - 1);
    int b = idx >> 18;
    float2 f = reinterpret_cast<const float2*>(flow)[idx];
    float xd = (float)w + f.x, yd = (float)h + f.y;
    float xff = floorf(xd), yff = floorf(yd);
    if (!(xff >= 0.0f && yff >= 0.0f &&
          xff <= (float)(W - 2) && yff <= (float)(H - 2))) return;
    int xf = (int)xff, yf = (int)yff;
    float ax = xd - xff, ay = yd - yff;
    float w0 = (1.f - ax) * (1.f - ay), w1 = ax * (1.f - ay);
    float w2 = (1.f - ax) * ay,         w3 = ax * ay;
    direct_splat(im0, out, b, h * W + w, xf, yf, w0, w1, w2, w3, 15u);
}

extern "C" void kernel_launch(void* const* d_in, const int* in_sizes, int n_in,
                              void* d_out, int out_size, void* d_ws, size_t ws_size,
                              hipStream_t stream) {
    const float* im0  = (const float*)d_in[0];
    const float* flow = (const float*)d_in[1];
    float* out = (float*)d_out;

    // ws layout: cnt[NBINS*CSTR] | ovf_cnt(16w) | ovf_list[OVF_CAP] | entries
    constexpr size_t cnt_words = (size_t)NBINS * CSTR;           // 16384
    constexpr size_t ovf_off   = cnt_words;                      // 64B-aligned
    constexpr size_t list_off  = cnt_words + 16;
    constexpr size_t ent_off   = list_off + OVF_CAP;
    constexpr size_t need_vals = (ent_off + (size_t)NBINS * CAP * REC) * 4;  // ~52.8 MB
    constexpr size_t need_wide = (list_off + (size_t)NBINS * CAP * 2) * 4;   // ~10.7 MB
    constexpr int total = B * HW;

    if (ws_size < need_wide) {
        hipMemsetAsync(out, 0, (size_t)out_size * sizeof(float), stream);
        warp_naive_kernel<<<(total + 255) / 256, 256, 0, stream>>>(im0, flow, out);
        return;
    }

    unsigned* cnt = (unsigned*)d_ws;
    unsigned* ovf_cnt  = cnt + ovf_off;
    unsigned* ovf_list = cnt + list_off;

    if (ws_size >= need_vals) {
        unsigned* entries = cnt + ent_off;
        // zero counters + overflow counter only (no out memset: accum
        // plain-stores every output element, fixup runs after)
        hipMemsetAsync(cnt, 0, (list_off) * 4, stream);
        bin2_kernel<<<total / 256, 256, 0, stream>>>(flow, im0, cnt, ovf_cnt, ovf_list, entries);
        accum_gather_kernel<<<NBINS, 256, 0, stream>>>(cnt, entries, out);
        fixup_kernel<<<16, 256, 0, stream>>>(flow, im0, ovf_cnt, ovf_list, out);
    } else {
        unsigned* entries = cnt + list_off;
        hipMemsetAsync(out, 0, (size_t)out_size * sizeof(float), stream);
        hipMemsetAsync(cnt, 0, cnt_words * 4, stream);
        bin_wide_kernel<<<total / 256, 256, 0, stream>>>(flow, im0, cnt, entries, out);
        dim3 agrid(NBINS, C / CPB);
        accum_wide_kernel<<<agrid, 256, 0, stream>>>(im0, cnt, entries, out);
    }
}